// Round 5
// baseline (178.667 us; speedup 1.0000x reference)
//
#include <hip/hip_runtime.h>

#define NSRC 20000
#define NDST 20000
#define NTOT 40000
#define ETOT 320000
#define ENEG 316800
#define NH 8
#define ND 16
#define NHD 128
#define BSTRIDE 136  // LDS row stride for transposed fc_w (pad: 128+8 bf16)

typedef __bf16 v8bf __attribute__((ext_vector_type(8)));
typedef float v4f __attribute__((ext_vector_type(4)));

// ---------------- workspace layout (bytes) ----------------
// [0, 80000)          count   (20000 int)   } zeroed
// [80000, 160000)     cursor  (20000 int)   } zeroed
// [160000, 480000)    flag    (320000 u8)   } zeroed  -> zero region = 480000 B
// [480000, 560064)    rowstart (20001 int, padded)
// [560064, 1840064)   csr (320000 int; bit31 = in-neg-set)
// [1840064, 1920064)  expcos (20000 f32)
// [1920064, 12160064) z (40000 x 128 bf16)
// [12160064, 13440064) el (40000 x 8 f32)
// [13440064, 14720064) er (40000 x 8 f32)

// MFMA bf16 GEMM z = feat @ fc_w (stored bf16) + fused el/er epilogue.
// Grid 753 blocks x 256: bid<625 -> 64-row GEMM strip; bid>=625 -> hist+flag.
// Per block: fc_w staged transposed bf16 in LDS; wave w computes rows
// [bid*64+w*16, +16) x all 128 cols via 4 k-steps x 8 n-tiles of
// mfma_f32_16x16x32_bf16. n-tile n == head n (16 cols each).
__global__ __launch_bounds__(256) void k_front(const float* __restrict__ A,
                                               const float* __restrict__ B,
                                               const float* __restrict__ attn_l,
                                               const float* __restrict__ attn_r,
                                               const int* __restrict__ edge_dst,
                                               const int* __restrict__ neg_idx,
                                               unsigned short* __restrict__ z,
                                               float* __restrict__ el,
                                               float* __restrict__ er,
                                               int* __restrict__ count,
                                               unsigned char* __restrict__ flag) {
    const int tid = threadIdx.x;
    const int bid = blockIdx.x;
    if (bid >= 625) {  // ---- hist + flag blocks (overlap with GEMM) ----
        int t0 = (bid - 625) * 256 + tid;  // 0..32767
        for (int i = t0; i < ETOT; i += 32768)
            atomicAdd(&count[edge_dst[i] - NSRC], 1);
        for (int i = t0; i < ENEG; i += 32768) flag[neg_idx[i]] = 1;
        return;
    }
    __shared__ __bf16 Bs[128 * BSTRIDE];  // Bs[n*BSTRIDE + k] = bf16(B[k][n])
    for (int i = tid; i < 4096; i += 256) {  // i-th float4 of B (row-major)
        float4 v = ((const float4*)B)[i];
        int k = (i * 4) >> 7;
        int n = (i * 4) & 127;
        Bs[(n + 0) * BSTRIDE + k] = (__bf16)v.x;
        Bs[(n + 1) * BSTRIDE + k] = (__bf16)v.y;
        Bs[(n + 2) * BSTRIDE + k] = (__bf16)v.z;
        Bs[(n + 3) * BSTRIDE + k] = (__bf16)v.w;
    }
    __syncthreads();
    const int w = tid >> 6, lane = tid & 63;
    const int ml = lane & 15, q = lane >> 4;
    const int gm = bid * 64 + w * 16 + ml;  // this lane's A row (m = lane&15)
    v4f acc[8];
#pragma unroll
    for (int n = 0; n < 8; ++n) acc[n] = (v4f){0.f, 0.f, 0.f, 0.f};
#pragma unroll
    for (int ks = 0; ks < 4; ++ks) {
        const int k0 = ks * 32 + q * 8;  // A[m][k]: k = quad*8 + j
        float4 f0 = *(const float4*)(A + (size_t)gm * 128 + k0);
        float4 f1 = *(const float4*)(A + (size_t)gm * 128 + k0 + 4);
        v8bf av;
        av[0] = (__bf16)f0.x; av[1] = (__bf16)f0.y;
        av[2] = (__bf16)f0.z; av[3] = (__bf16)f0.w;
        av[4] = (__bf16)f1.x; av[5] = (__bf16)f1.y;
        av[6] = (__bf16)f1.z; av[7] = (__bf16)f1.w;
#pragma unroll
        for (int n = 0; n < 8; ++n) {
            v8bf bv = *(const v8bf*)(&Bs[(n * 16 + ml) * BSTRIDE + k0]);
            acc[n] = __builtin_amdgcn_mfma_f32_16x16x32_bf16(av, bv, acc[n], 0, 0, 0);
        }
    }
    // ---- epilogue: z store (bf16 RNE) + el/er from fp32 accumulators ----
    // C layout: row = q*4 + reg, col = n*16 + ml  (head = n)
    const int rowbase = bid * 64 + w * 16 + q * 4;
#pragma unroll
    for (int n = 0; n < 8; ++n) {
        float alv = attn_l[n * 16 + ml];
        float arv = attn_r[n * 16 + ml];
#pragma unroll
        for (int r = 0; r < 4; ++r) {
            float v = acc[n][r];
            unsigned int u = __float_as_uint(v);
            unsigned int b = (u + 0x7fffu + ((u >> 16) & 1u)) >> 16;  // RNE
            z[(size_t)(rowbase + r) * NHD + n * 16 + ml] = (unsigned short)b;
            float pl = v * alv, pr = v * arv;
#pragma unroll
            for (int s = 1; s <= 8; s <<= 1) {  // reduce 16 cols (lane bits 0..3)
                pl += __shfl_xor(pl, s, 64);
                pr += __shfl_xor(pr, s, 64);
            }
            if (ml == 0) {
                el[(rowbase + r) * NH + n] = pl;
                er[(rowbase + r) * NH + n] = pr;
            }
        }
    }
}

// single-block scan: each thread owns 20 contiguous counts, shfl block scan
__global__ __launch_bounds__(1024) void k_scan(const int* __restrict__ count,
                                               int* __restrict__ rowstart) {
    __shared__ int wsum[16];
    const int tid = threadIdx.x;
    const int lane = tid & 63, w = tid >> 6;
    const int base = tid * 20;
    int c[20];
    int s = 0;
#pragma unroll
    for (int k = 0; k < 20; ++k) {
        int i = base + k;
        int v = (i < NDST) ? count[i] : 0;
        c[k] = s;
        s += v;
    }
    int v = s;
    for (int sh = 1; sh < 64; sh <<= 1) {
        int t = __shfl_up(v, sh, 64);
        if (lane >= sh) v += t;
    }
    if (lane == 63) wsum[w] = v;
    __syncthreads();
    int carry = 0;
    for (int ww = 0; ww < w; ++ww) carry += wsum[ww];
    int excl = carry + v - s;
#pragma unroll
    for (int k = 0; k < 20; ++k) {
        int i = base + k;
        if (i < NDST) rowstart[i] = excl + c[k];
    }
    if (tid == 1023) rowstart[NDST] = carry + v;  // = ETOT
}

__global__ __launch_bounds__(256) void k_scatter(const int* __restrict__ edge_src,
                                                 const int* __restrict__ edge_dst,
                                                 const unsigned char* __restrict__ flag,
                                                 const int* __restrict__ rowstart,
                                                 int* __restrict__ cursor,
                                                 int* __restrict__ csr) {
    int i = blockIdx.x * 256 + threadIdx.x;
    if (i >= ETOT) return;
    int d = edge_dst[i] - NSRC;
    int pos = rowstart[d] + atomicAdd(&cursor[d], 1);
    int v = edge_src[i];
    if (flag[i]) v |= (int)0x80000000u;
    csr[pos] = v;
}

// One wave per dst node, chunk = 16 edges, zero LDS. z is bf16 (4 B/lane
// gathers, zr[] = 16 VGPRs). Structure is allocator-fragile: do NOT add
// LDS/barriers/atomics to this kernel (round-3 regression).
__global__ __launch_bounds__(256) void k_agg(const int* __restrict__ rowstart,
                                             const int* __restrict__ csr,
                                             const unsigned short* __restrict__ z,
                                             const float* __restrict__ el,
                                             const float* __restrict__ er,
                                             const float* __restrict__ bias,
                                             const float* __restrict__ prelu_a,
                                             float* __restrict__ out,
                                             float* __restrict__ expcos) {
    const int lane = threadIdx.x & 63;
    const int wid = threadIdx.x >> 6;
    const int d = (blockIdx.x << 2) + wid;  // grid = NDST/4 exactly

    const int g = NSRC + d;
    const int hl = lane >> 3;
    const int j8 = lane & 7;
    const float erd = er[g * NH + hl];
    const float aslope = prelu_a[0];
    const float NEGINF = -__builtin_inff();

    float mF = NEGINF, lF = 0.f, mN = NEGINF, lN = 0.f;
    float aF0 = 0.f, aF1 = 0.f, aN0 = 0.f, aN1 = 0.f;
    const int rs = rowstart[d];
    const int deg = rowstart[d + 1] - rs;

    for (int base = 0; base < deg; base += 16) {
        const int j0 = base + j8, j1 = base + 8 + j8;
        int ent0 = (j0 < deg) ? csr[rs + j0] : g;
        int ent1 = (j1 < deg) ? csr[rs + j1] : g;
        unsigned int zr[16];  // bf16x2 per lane per edge-row
#pragma unroll
        for (int jj = 0; jj < 16; ++jj) {
            int entry = __shfl((jj < 8) ? ent0 : ent1, jj & 7, 64);
            zr[jj] = *(const unsigned int*)(z + ((size_t)(entry & 0x7FFFFFFF) << 7) + 2 * lane);
        }
        float e0 = el[(size_t)(ent0 & 0x7FFFFFFF) * NH + hl] + erd;
        float e1 = el[(size_t)(ent1 & 0x7FFFFFFF) * NH + hl] + erd;
        e0 = (e0 >= 0.f) ? e0 : 0.2f * e0;
        e1 = (e1 >= 0.f) ? e1 : 0.2f * e1;
        float ev0 = (j0 < deg) ? e0 : NEGINF;
        float ev1 = (j1 < deg) ? e1 : NEGINF;
        const int fl0 = (j0 < deg) && (ent0 < 0);
        const int fl1 = (j1 < deg) && (ent1 < 0);
        float cmF = fmaxf(ev0, ev1);
        float cmN = fmaxf(fl0 ? ev0 : NEGINF, fl1 ? ev1 : NEGINF);
#pragma unroll
        for (int s = 1; s <= 4; s <<= 1) {
            cmF = fmaxf(cmF, __shfl_xor(cmF, s, 64));
            cmN = fmaxf(cmN, __shfl_xor(cmN, s, 64));
        }
        float nmF = fmaxf(mF, cmF);
        float scF = (nmF == mF) ? 1.f : __expf(mF - nmF);
        mF = nmF;
        float nmN = fmaxf(mN, cmN);
        float scN = (nmN == mN) ? 1.f : __expf(mN - nmN);
        mN = nmN;
        float wf0 = __expf(ev0 - mF);  // 0 for pad slots (mF finite)
        float wf1 = __expf(ev1 - mF);
        float wn0 = fl0 ? __expf(ev0 - mN) : 0.f;
        float wn1 = fl1 ? __expf(ev1 - mN) : 0.f;
        lF = lF * scF + wf0 + wf1;
        lN = lN * scN + wn0 + wn1;
        float w0 = fl0 ? -wf0 : wf0;  // sign bit = neg-graph membership
        float w1 = fl1 ? -wf1 : wf1;
        float sNh = __expf(mF - mN);  // wf -> wn conversion (per head)
        aF0 *= scF; aF1 *= scF; aN0 *= scN; aN1 *= scN;
#pragma unroll
        for (int jj = 0; jj < 16; ++jj) {
            float v = __shfl((jj < 8) ? w0 : w1, (lane & 56) | (jj & 7), 64);
            float wf = fabsf(v);
            float wn = (v < 0.f) ? wf * sNh : 0.f;
            float zx = __uint_as_float(zr[jj] << 16);
            float zy = __uint_as_float(zr[jj] & 0xffff0000u);
            aF0 = fmaf(wf, zx, aF0);
            aF1 = fmaf(wf, zy, aF1);
            aN0 = fmaf(wn, zx, aN0);
            aN1 = fmaf(wn, zy, aN1);
        }
    }

    // self-loop (in both graphs)
    {
        float e = el[g * NH + hl] + erd;
        e = (e >= 0.f) ? e : 0.2f * e;
        float nmF = fmaxf(mF, e);
        float scF = (nmF == mF) ? 1.f : __expf(mF - nmF);
        lF *= scF; aF0 *= scF; aF1 *= scF; mF = nmF;
        float wf = __expf(e - mF);
        float nmN = fmaxf(mN, e);
        float scN = (nmN == mN) ? 1.f : __expf(mN - nmN);
        lN *= scN; aN0 *= scN; aN1 *= scN; mN = nmN;
        float wn = __expf(e - mN);
        if (j8 == 0) { lF += wf; lN += wn; }  // denom: once per head group
        unsigned int zv = *(const unsigned int*)(z + ((size_t)g << 7) + 2 * lane);
        float zx = __uint_as_float(zv << 16);
        float zy = __uint_as_float(zv & 0xffff0000u);
        aF0 = fmaf(wf, zx, aF0);
        aF1 = fmaf(wf, zy, aF1);
        aN0 = fmaf(wn, zx, aN0);
        aN1 = fmaf(wn, zy, aN1);
    }

    // denominators per head group (reduce over j8 bits)
#pragma unroll
    for (int s = 1; s <= 4; s <<= 1) {
        lF += __shfl_xor(lF, s, 64);
        lN += __shfl_xor(lN, s, 64);
    }
    const int c0 = 2 * lane;
    float b0 = bias[c0], b1 = bias[c0 + 1];
    float rF0 = aF0 / lF + b0, rF1 = aF1 / lF + b1;
    float rN0 = aN0 / lN + b0, rN1 = aN1 / lN + b1;
    rF0 = (rF0 >= 0.f) ? rF0 : aslope * rF0;
    rF1 = (rF1 >= 0.f) ? rF1 : aslope * rF1;
    rN0 = (rN0 >= 0.f) ? rN0 : aslope * rN0;
    rN1 = (rN1 >= 0.f) ? rN1 : aslope * rN1;
    // head mean: sum over heads (bits 3..5), /8
#pragma unroll
    for (int s = 8; s <= 32; s <<= 1) {
        rF0 += __shfl_xor(rF0, s, 64);
        rF1 += __shfl_xor(rF1, s, 64);
        rN0 += __shfl_xor(rN0, s, 64);
        rN1 += __shfl_xor(rN1, s, 64);
    }
    float hF0 = rF0 * 0.125f, hF1 = rF1 * 0.125f;
    float hN0 = rN0 * 0.125f, hN1 = rN1 * 0.125f;
    if (lane < 8) {
        out[1 + d * ND + 2 * lane] = hF0;
        out[1 + d * ND + 2 * lane + 1] = hF1;
    }
    float num = hF0 * hN0 + hF1 * hN1;
    float na = hF0 * hF0 + hF1 * hF1;
    float nb = hN0 * hN0 + hN1 * hN1;
#pragma unroll
    for (int s = 1; s <= 4; s <<= 1) {
        num += __shfl_xor(num, s, 64);
        na += __shfl_xor(na, s, 64);
        nb += __shfl_xor(nb, s, 64);
    }
    if (lane == 0) {
        float cosv = num / (fmaxf(sqrtf(na), 1e-8f) * fmaxf(sqrtf(nb), 1e-8f));
        expcos[d] = __expf(cosv / 0.7f);
    }
}

__global__ __launch_bounds__(1024) void k_loss(const float* __restrict__ expcos,
                                               float* __restrict__ out) {
    __shared__ float sbuf[16];
    float s = 0.f;
    for (int i = threadIdx.x; i < NDST; i += 1024) s += expcos[i];
    for (int sh = 1; sh < 64; sh <<= 1) s += __shfl_xor(s, sh, 64);
    if ((threadIdx.x & 63) == 0) sbuf[threadIdx.x >> 6] = s;
    __syncthreads();
    if (threadIdx.x < 16) {
        float t = sbuf[threadIdx.x];
        for (int sh = 1; sh < 16; sh <<= 1) t += __shfl_xor(t, sh, 16);
        if (threadIdx.x == 0) out[0] = logf(t);
    }
}

extern "C" void kernel_launch(void* const* d_in, const int* in_sizes, int n_in,
                              void* d_out, int out_size, void* d_ws, size_t ws_size,
                              hipStream_t stream) {
    const float* feat = (const float*)d_in[0];
    const float* fc_w = (const float*)d_in[1];
    const float* attn_l = (const float*)d_in[2];
    const float* attn_r = (const float*)d_in[3];
    const float* bias = (const float*)d_in[4];
    const float* prelu_a = (const float*)d_in[5];
    const int* edge_src = (const int*)d_in[6];
    const int* edge_dst = (const int*)d_in[7];
    const int* neg_idx = (const int*)d_in[8];
    float* out = (float*)d_out;

    char* ws = (char*)d_ws;
    int* count = (int*)(ws + 0);
    int* cursor = (int*)(ws + 80000);
    unsigned char* flag = (unsigned char*)(ws + 160000);
    int* rowstart = (int*)(ws + 480000);
    int* csr = (int*)(ws + 560064);
    float* expcos = (float*)(ws + 1840064);
    unsigned short* z = (unsigned short*)(ws + 1920064);
    float* el = (float*)(ws + 12160064);
    float* er = (float*)(ws + 13440064);

    hipMemsetAsync(d_ws, 0, 480000, stream);  // count + cursor + flag
    k_front<<<753, 256, 0, stream>>>(feat, fc_w, attn_l, attn_r, edge_dst,
                                     neg_idx, z, el, er, count, flag);
    k_scan<<<1, 1024, 0, stream>>>(count, rowstart);
    k_scatter<<<(ETOT + 255) / 256, 256, 0, stream>>>(edge_src, edge_dst, flag,
                                                      rowstart, cursor, csr);
    k_agg<<<NDST / 4, 256, 0, stream>>>(rowstart, csr, z, el, er, bias, prelu_a,
                                        out, expcos);
    k_loss<<<1, 1024, 0, stream>>>(expcos, out);
}

// Round 6
// 157.503 us; speedup vs baseline: 1.1344x; 1.1344x over previous
//
#include <hip/hip_runtime.h>

#define NSRC 20000
#define NDST 20000
#define NTOT 40000
#define ETOT 320000
#define ENEG 316800
#define NH 8
#define ND 16
#define NHD 128
#define BCAP 64      // fixed bucket capacity per dst (Poisson(16): P(>63) ~ 1e-20)
#define BSTRIDE 136  // LDS row stride for transposed fc_w (pad: 128+8 bf16)

typedef __bf16 v8bf __attribute__((ext_vector_type(8)));
typedef float v4f __attribute__((ext_vector_type(4)));

// ---------------- workspace layout (bytes) ----------------
// [0, 80000)           cursor/deg (20000 int)  } zeroed
// [80000, 400000)      flag (320000 u8)        } zeroed  -> zero region 400000 B
// [400000, 5520000)    csr buckets (20000 x 64 int; bit31 = in-neg-set)
// [5520000, 5600000)   expcos (20000 f32)
// [5600000, 15840000)  z (40000 x 128 bf16)
// [15840000, 17120000) el (40000 x 8 f32)
// [17120000, 18400000) er (40000 x 8 f32)

// MFMA bf16 GEMM z = feat @ fc_w + fused el/er epilogue; extra blocks fill
// the neg-edge flag (independent, overlapped). Grid 753 x 256.
__global__ __launch_bounds__(256) void k_front(const float* __restrict__ A,
                                               const float* __restrict__ B,
                                               const float* __restrict__ attn_l,
                                               const float* __restrict__ attn_r,
                                               const int* __restrict__ neg_idx,
                                               unsigned short* __restrict__ z,
                                               float* __restrict__ el,
                                               float* __restrict__ er,
                                               unsigned char* __restrict__ flag) {
    const int tid = threadIdx.x;
    const int bid = blockIdx.x;
    if (bid >= 625) {  // ---- neg-flag blocks ----
        int t0 = (bid - 625) * 256 + tid;  // 0..32767
        for (int i = t0; i < ENEG; i += 32768) flag[neg_idx[i]] = 1;
        return;
    }
    __shared__ __bf16 Bs[128 * BSTRIDE];  // Bs[n*BSTRIDE + k] = bf16(B[k][n])
    for (int i = tid; i < 4096; i += 256) {  // i-th float4 of B (row-major)
        float4 v = ((const float4*)B)[i];
        int k = (i * 4) >> 7;
        int n = (i * 4) & 127;
        Bs[(n + 0) * BSTRIDE + k] = (__bf16)v.x;
        Bs[(n + 1) * BSTRIDE + k] = (__bf16)v.y;
        Bs[(n + 2) * BSTRIDE + k] = (__bf16)v.z;
        Bs[(n + 3) * BSTRIDE + k] = (__bf16)v.w;
    }
    __syncthreads();
    const int w = tid >> 6, lane = tid & 63;
    const int ml = lane & 15, q = lane >> 4;
    const int gm = bid * 64 + w * 16 + ml;  // this lane's A row (m = lane&15)
    v4f acc[8];
#pragma unroll
    for (int n = 0; n < 8; ++n) acc[n] = (v4f){0.f, 0.f, 0.f, 0.f};
#pragma unroll
    for (int ks = 0; ks < 4; ++ks) {
        const int k0 = ks * 32 + q * 8;  // A[m][k]: k = quad*8 + j
        float4 f0 = *(const float4*)(A + (size_t)gm * 128 + k0);
        float4 f1 = *(const float4*)(A + (size_t)gm * 128 + k0 + 4);
        v8bf av;
        av[0] = (__bf16)f0.x; av[1] = (__bf16)f0.y;
        av[2] = (__bf16)f0.z; av[3] = (__bf16)f0.w;
        av[4] = (__bf16)f1.x; av[5] = (__bf16)f1.y;
        av[6] = (__bf16)f1.z; av[7] = (__bf16)f1.w;
#pragma unroll
        for (int n = 0; n < 8; ++n) {
            v8bf bv = *(const v8bf*)(&Bs[(n * 16 + ml) * BSTRIDE + k0]);
            acc[n] = __builtin_amdgcn_mfma_f32_16x16x32_bf16(av, bv, acc[n], 0, 0, 0);
        }
    }
    // ---- epilogue: z store (bf16 RNE) + el/er from fp32 accumulators ----
    // C layout: row = q*4 + reg, col = n*16 + ml  (head = n)
    const int rowbase = bid * 64 + w * 16 + q * 4;
#pragma unroll
    for (int n = 0; n < 8; ++n) {
        float alv = attn_l[n * 16 + ml];
        float arv = attn_r[n * 16 + ml];
#pragma unroll
        for (int r = 0; r < 4; ++r) {
            float v = acc[n][r];
            unsigned int u = __float_as_uint(v);
            unsigned int b = (u + 0x7fffu + ((u >> 16) & 1u)) >> 16;  // RNE
            z[(size_t)(rowbase + r) * NHD + n * 16 + ml] = (unsigned short)b;
            float pl = v * alv, pr = v * arv;
#pragma unroll
            for (int s = 1; s <= 8; s <<= 1) {  // reduce 16 cols (lane bits 0..3)
                pl += __shfl_xor(pl, s, 64);
                pr += __shfl_xor(pr, s, 64);
            }
            if (ml == 0) {
                el[(rowbase + r) * NH + n] = pl;
                er[(rowbase + r) * NH + n] = pr;
            }
        }
    }
}

// bucket scatter: slot within dst from atomicAdd(cursor); no scan needed.
__global__ __launch_bounds__(256) void k_scatter(const int* __restrict__ edge_src,
                                                 const int* __restrict__ edge_dst,
                                                 const unsigned char* __restrict__ flag,
                                                 int* __restrict__ cursor,
                                                 int* __restrict__ csr) {
    int i = blockIdx.x * 256 + threadIdx.x;
    if (i >= ETOT) return;
    int d = edge_dst[i] - NSRC;
    int slot = atomicAdd(&cursor[d], 1);
    int v = edge_src[i];
    if (flag[i]) v |= (int)0x80000000u;
    if (slot < BCAP) csr[d * BCAP + slot] = v;
}

// One wave per dst node, chunk = 16 edges, zero LDS, bf16 z.
// Shared-max softmax: neg graph is a subset of the full graph, so the
// full-graph running max mF serves both (shift invariance) — wn == wf for
// neg-flagged edges. Structure is allocator-fragile: do NOT add LDS /
// barriers / atomics to this kernel (round-3 regression).
__global__ __launch_bounds__(256) void k_agg(const int* __restrict__ degarr,
                                             const int* __restrict__ csr,
                                             const unsigned short* __restrict__ z,
                                             const float* __restrict__ el,
                                             const float* __restrict__ er,
                                             const float* __restrict__ bias,
                                             const float* __restrict__ prelu_a,
                                             float* __restrict__ out,
                                             float* __restrict__ expcos) {
    const int lane = threadIdx.x & 63;
    const int wid = threadIdx.x >> 6;
    const int d = (blockIdx.x << 2) + wid;  // grid = NDST/4 exactly

    const int g = NSRC + d;
    const int hl = lane >> 3;
    const int j8 = lane & 7;
    const int rs = d * BCAP;
    const int deg = degarr[d];
    const float erd = er[g * NH + hl];
    const float aslope = prelu_a[0];
    const float NEGINF = -__builtin_inff();

    float mF = NEGINF, lF = 0.f, lN = 0.f;
    float aF0 = 0.f, aF1 = 0.f, aN0 = 0.f, aN1 = 0.f;

    for (int base = 0; base < deg; base += 16) {
        const int j0 = base + j8, j1 = base + 8 + j8;
        int ent0 = (j0 < deg) ? csr[rs + j0] : g;
        int ent1 = (j1 < deg) ? csr[rs + j1] : g;
        unsigned int zr[16];  // bf16x2 per lane per edge-row
#pragma unroll
        for (int jj = 0; jj < 16; ++jj) {
            int entry = __shfl((jj < 8) ? ent0 : ent1, jj & 7, 64);
            zr[jj] = *(const unsigned int*)(z + ((size_t)(entry & 0x7FFFFFFF) << 7) + 2 * lane);
        }
        float e0 = el[(size_t)(ent0 & 0x7FFFFFFF) * NH + hl] + erd;
        float e1 = el[(size_t)(ent1 & 0x7FFFFFFF) * NH + hl] + erd;
        e0 = (e0 >= 0.f) ? e0 : 0.2f * e0;
        e1 = (e1 >= 0.f) ? e1 : 0.2f * e1;
        float ev0 = (j0 < deg) ? e0 : NEGINF;
        float ev1 = (j1 < deg) ? e1 : NEGINF;
        const int fl0 = (j0 < deg) && (ent0 < 0);
        const int fl1 = (j1 < deg) && (ent1 < 0);
        float cm = fmaxf(ev0, ev1);
#pragma unroll
        for (int s = 1; s <= 4; s <<= 1) cm = fmaxf(cm, __shfl_xor(cm, s, 64));
        float nm = fmaxf(mF, cm);
        float sc = (nm == mF) ? 1.f : __expf(mF - nm);
        mF = nm;
        float wf0 = __expf(ev0 - mF);  // 0 for pad slots (mF finite)
        float wf1 = __expf(ev1 - mF);
        lF = lF * sc + wf0 + wf1;
        lN = lN * sc + (fl0 ? wf0 : 0.f) + (fl1 ? wf1 : 0.f);
        float w0 = fl0 ? -wf0 : wf0;  // sign bit = neg-graph membership
        float w1 = fl1 ? -wf1 : wf1;
        aF0 *= sc; aF1 *= sc; aN0 *= sc; aN1 *= sc;
#pragma unroll
        for (int jj = 0; jj < 16; ++jj) {
            float v = __shfl((jj < 8) ? w0 : w1, (lane & 56) | (jj & 7), 64);
            float wf = fabsf(v);
            float wn = (v < 0.f) ? wf : 0.f;
            float zx = __uint_as_float(zr[jj] << 16);
            float zy = __uint_as_float(zr[jj] & 0xffff0000u);
            aF0 = fmaf(wf, zx, aF0);
            aF1 = fmaf(wf, zy, aF1);
            aN0 = fmaf(wn, zx, aN0);
            aN1 = fmaf(wn, zy, aN1);
        }
    }

    // self-loop (in both graphs, shares mF)
    {
        float e = el[g * NH + hl] + erd;
        e = (e >= 0.f) ? e : 0.2f * e;
        float nm = fmaxf(mF, e);
        float sc = (nm == mF) ? 1.f : __expf(mF - nm);
        lF *= sc; lN *= sc;
        aF0 *= sc; aF1 *= sc; aN0 *= sc; aN1 *= sc;
        mF = nm;
        float wf = __expf(e - mF);
        if (j8 == 0) { lF += wf; lN += wf; }  // denom: once per head group
        unsigned int zv = *(const unsigned int*)(z + ((size_t)g << 7) + 2 * lane);
        float zx = __uint_as_float(zv << 16);
        float zy = __uint_as_float(zv & 0xffff0000u);
        aF0 = fmaf(wf, zx, aF0);
        aF1 = fmaf(wf, zy, aF1);
        aN0 = fmaf(wf, zx, aN0);
        aN1 = fmaf(wf, zy, aN1);
    }

    // denominators per head group (reduce over j8 bits)
#pragma unroll
    for (int s = 1; s <= 4; s <<= 1) {
        lF += __shfl_xor(lF, s, 64);
        lN += __shfl_xor(lN, s, 64);
    }
    const int c0 = 2 * lane;
    float b0 = bias[c0], b1 = bias[c0 + 1];
    float rF0 = aF0 / lF + b0, rF1 = aF1 / lF + b1;
    float rN0 = aN0 / lN + b0, rN1 = aN1 / lN + b1;
    rF0 = (rF0 >= 0.f) ? rF0 : aslope * rF0;
    rF1 = (rF1 >= 0.f) ? rF1 : aslope * rF1;
    rN0 = (rN0 >= 0.f) ? rN0 : aslope * rN0;
    rN1 = (rN1 >= 0.f) ? rN1 : aslope * rN1;
    // head mean: sum over heads (bits 3..5), /8
#pragma unroll
    for (int s = 8; s <= 32; s <<= 1) {
        rF0 += __shfl_xor(rF0, s, 64);
        rF1 += __shfl_xor(rF1, s, 64);
        rN0 += __shfl_xor(rN0, s, 64);
        rN1 += __shfl_xor(rN1, s, 64);
    }
    float hF0 = rF0 * 0.125f, hF1 = rF1 * 0.125f;
    float hN0 = rN0 * 0.125f, hN1 = rN1 * 0.125f;
    if (lane < 8) {
        out[1 + d * ND + 2 * lane] = hF0;
        out[1 + d * ND + 2 * lane + 1] = hF1;
    }
    float num = hF0 * hN0 + hF1 * hN1;
    float na = hF0 * hF0 + hF1 * hF1;
    float nb = hN0 * hN0 + hN1 * hN1;
#pragma unroll
    for (int s = 1; s <= 4; s <<= 1) {
        num += __shfl_xor(num, s, 64);
        na += __shfl_xor(na, s, 64);
        nb += __shfl_xor(nb, s, 64);
    }
    if (lane == 0) {
        float cosv = num / (fmaxf(sqrtf(na), 1e-8f) * fmaxf(sqrtf(nb), 1e-8f));
        expcos[d] = __expf(cosv / 0.7f);
    }
}

__global__ __launch_bounds__(1024) void k_loss(const float* __restrict__ expcos,
                                               float* __restrict__ out) {
    __shared__ float sbuf[16];
    float s = 0.f;
    for (int i = threadIdx.x; i < NDST; i += 1024) s += expcos[i];
    for (int sh = 1; sh < 64; sh <<= 1) s += __shfl_xor(s, sh, 64);
    if ((threadIdx.x & 63) == 0) sbuf[threadIdx.x >> 6] = s;
    __syncthreads();
    if (threadIdx.x < 16) {
        float t = sbuf[threadIdx.x];
        for (int sh = 1; sh < 16; sh <<= 1) t += __shfl_xor(t, sh, 16);
        if (threadIdx.x == 0) out[0] = logf(t);
    }
}

extern "C" void kernel_launch(void* const* d_in, const int* in_sizes, int n_in,
                              void* d_out, int out_size, void* d_ws, size_t ws_size,
                              hipStream_t stream) {
    const float* feat = (const float*)d_in[0];
    const float* fc_w = (const float*)d_in[1];
    const float* attn_l = (const float*)d_in[2];
    const float* attn_r = (const float*)d_in[3];
    const float* bias = (const float*)d_in[4];
    const float* prelu_a = (const float*)d_in[5];
    const int* edge_src = (const int*)d_in[6];
    const int* edge_dst = (const int*)d_in[7];
    const int* neg_idx = (const int*)d_in[8];
    float* out = (float*)d_out;

    char* ws = (char*)d_ws;
    int* cursor = (int*)(ws + 0);
    unsigned char* flag = (unsigned char*)(ws + 80000);
    int* csr = (int*)(ws + 400000);
    float* expcos = (float*)(ws + 5520000);
    unsigned short* z = (unsigned short*)(ws + 5600000);
    float* el = (float*)(ws + 15840000);
    float* er = (float*)(ws + 17120000);

    hipMemsetAsync(d_ws, 0, 400000, stream);  // cursor + flag
    k_front<<<753, 256, 0, stream>>>(feat, fc_w, attn_l, attn_r, neg_idx,
                                     z, el, er, flag);
    k_scatter<<<(ETOT + 255) / 256, 256, 0, stream>>>(edge_src, edge_dst, flag,
                                                      cursor, csr);
    k_agg<<<NDST / 4, 256, 0, stream>>>(cursor, csr, z, el, er, bias, prelu_a,
                                        out, expcos);
    k_loss<<<1, 1024, 0, stream>>>(expcos, out);
}